// Round 1
// baseline (665.735 us; speedup 1.0000x reference)
//
#include <hip/hip_runtime.h>
#include <math.h>

// BEV (4,128,512,512) f32 -> cylindrical (4,128,64,2048) f32.
// FUSED single kernel: one block per (b,c) image. Block computes the 2048
// bilinear circle samples into LDS (8 KB), syncs once, then each thread
// hoists its two float4 column slices into registers and streams the
// 64-row broadcast (512 KB/block) straight to out. No workspace use at all.
//
// Rationale (rocprof): top dispatches are 2-GiB fillBufferAligned poisons of
// the workspace (~336 us each); my kernels' hand-computed cost is <100 us.
// Eliminating d_ws both removes the intermediate traffic and tests whether
// the 662-us floor is the workspace poison inside the timed region.

namespace {
constexpr int BB = 4, CC = 128, HB = 512, WB = 512, HC = 64, WC = 2048;
constexpr float XMIN = -50.0f, XMAX = 50.0f, YMIN = -50.0f, YMAX = 50.0f;
constexpr float MAX_RANGE = 50.0f;

__device__ __forceinline__ float sample_col(const float* __restrict__ img, int j) {
    const float PI = 3.14159265358979323846f;
    float phi = -PI + (float)j * (2.0f * PI / (float)(WC - 1));
    float xg = MAX_RANGE * cosf(phi);
    float yg = MAX_RANGE * sinf(phi);
    float x = (xg - XMIN) * ((float)(WB - 1) / (XMAX - XMIN));
    float y = (YMAX - yg) * ((float)(HB - 1) / (YMAX - YMIN));
    float fx0 = floorf(x), fy0 = floorf(y);
    int x0 = (int)fx0, y0 = (int)fy0;
    int x1 = x0 + 1, y1 = y0 + 1;
    float wx1 = x - fx0, wx0 = 1.0f - wx1;
    float wy1 = y - fy0, wy0 = 1.0f - wy1;

    float acc = 0.0f;
    {   // (x0, y0)
        bool v = (x0 >= 0) & (x0 < WB) & (y0 >= 0) & (y0 < HB);
        int xc = min(max(x0, 0), WB - 1), yc = min(max(y0, 0), HB - 1);
        acc += img[yc * WB + xc] * (v ? wx0 * wy0 : 0.0f);
    }
    {   // (x1, y0)
        bool v = (x1 >= 0) & (x1 < WB) & (y0 >= 0) & (y0 < HB);
        int xc = min(max(x1, 0), WB - 1), yc = min(max(y0, 0), HB - 1);
        acc += img[yc * WB + xc] * (v ? wx1 * wy0 : 0.0f);
    }
    {   // (x0, y1)
        bool v = (x0 >= 0) & (x0 < WB) & (y1 >= 0) & (y1 < HB);
        int xc = min(max(x0, 0), WB - 1), yc = min(max(y1, 0), HB - 1);
        acc += img[yc * WB + xc] * (v ? wx0 * wy1 : 0.0f);
    }
    {   // (x1, y1)
        bool v = (x1 >= 0) & (x1 < WB) & (y1 >= 0) & (y1 < HB);
        int xc = min(max(x1, 0), WB - 1), yc = min(max(y1, 0), HB - 1);
        acc += img[yc * WB + xc] * (v ? wx1 * wy1 : 0.0f);
    }
    return acc;
}
} // namespace

// One block per (b,c): 512 blocks x 256 threads.
// Phase A: 8 samples/thread -> LDS col[2048] (8 KB).
// Phase B: each thread holds col float4 slots {tid, tid+256} in registers and
// writes them to all 64 rows: 128 coalesced float4 stores/thread.
__global__ __launch_bounds__(256) void fused_bev2cyl(const float* __restrict__ bev,
                                                     float* __restrict__ out) {
    __shared__ __align__(16) float col[WC];

    const int bc  = blockIdx.x;                       // 0..511
    const int tid = threadIdx.x;                      // 0..255
    const float* img = bev + (size_t)bc * (size_t)(HB * WB);

    #pragma unroll
    for (int k = 0; k < WC / 256; ++k) {              // 8 samples per thread
        int j = tid + k * 256;
        col[j] = sample_col(img, j);
    }
    __syncthreads();

    const float4* colv = (const float4*)col;          // 512 float4 slots
    float4 va = colv[tid];                            // slot tid
    float4 vb = colv[tid + 256];                      // slot tid+256

    float4* o = (float4*)out + (size_t)bc * (size_t)(HC * WC / 4);
    #pragma unroll 4
    for (int h = 0; h < HC; ++h) {                    // 64 rows x 8 KB
        o[h * (WC / 4) + tid]       = va;
        o[h * (WC / 4) + 256 + tid] = vb;
    }
}

extern "C" void kernel_launch(void* const* d_in, const int* in_sizes, int n_in,
                              void* d_out, int out_size, void* d_ws, size_t ws_size,
                              hipStream_t stream) {
    (void)d_ws; (void)ws_size;
    const float* bev = (const float*)d_in[0];
    float* out = (float*)d_out;
    fused_bev2cyl<<<dim3(BB * CC), dim3(256), 0, stream>>>(bev, out);
}